// Round 10
// baseline (255.213 us; speedup 1.0000x reference)
//
#include <hip/hip_runtime.h>
#include <hip/hip_bf16.h>

#define N 384
#define HIDN 128
#define NHD 8
#define DHD 16
#define NRB 64
#define CUTF 10.0f

// ws layout (float slots)
#define WS_V 0
#define WS_QPB (WS_V + N*HIDN)                 // bf16 buffer: head-major [h][n][c]
#define WS_KPB (WS_QPB + N*NHD*HIDN/2)        // bf16 buffer: head-major [h][n][c]
#define WS_GATE (WS_KPB + N*NHD*HIDN/2)
#define WS_UPD (WS_GATE + N*NHD)
#define WS_SCORES (WS_UPD + N*HIDN)
#define WS_W2BF (WS_SCORES + NHD*N*N)         // bf16 buffer: 128*128 shorts (W2^T)

typedef short bf16x8 __attribute__((ext_vector_type(8)));
typedef float floatx4 __attribute__((ext_vector_type(4)));
#define MFMA16(a, b, c) __builtin_amdgcn_mfma_f32_16x16x32_bf16(a, b, c, 0, 0, 0)

__device__ __forceinline__ float siluf(float x) { return x / (1.0f + __expf(-x)); }
__device__ __forceinline__ float silu_fast(float x) {
    return x * __builtin_amdgcn_rcpf(1.0f + __expf(-x));
}
__device__ __forceinline__ short f2bf(float f) {
    unsigned int b = __float_as_uint(f);
    unsigned int r = (b + 0x7fffu + ((b >> 16) & 1u)) >> 16;
    return (short)r;
}
__device__ __forceinline__ float bf2f(short s) {
    return __uint_as_float(((unsigned int)(unsigned short)s) << 16);
}
// packed f32x2 -> bf16x2 (RNE), 1 instr instead of 2x5
__device__ __forceinline__ unsigned int cvt_pk_bf16(float lo, float hi) {
    unsigned int r;
    asm("v_cvt_pk_bf16_f32 %0, %1, %2" : "=v"(r) : "v"(lo), "v"(hi));
    return r;
}
__device__ __forceinline__ float wave_sum(float v) {
    for (int o = 32; o; o >>= 1) v += __shfl_down(v, o, 64);
    return v;
}

// K1: fused qkv + Qp/Kp(bf16, head-major) + gates + W2^T bf16 pre-transpose
__global__ __launch_bounds__(128) void k_pre(const float* __restrict__ ef,
    const float* __restrict__ wq, const float* __restrict__ wk, const float* __restrict__ wv,
    const float* __restrict__ aw1, const float* __restrict__ aw2,
    const float* __restrict__ gw1, const float* __restrict__ gb1,
    const float* __restrict__ gw2, const float* __restrict__ gb2,
    float* __restrict__ v, unsigned short* __restrict__ Qpb,
    unsigned short* __restrict__ Kpb, float* __restrict__ gates,
    unsigned short* __restrict__ w2bf) {
    __shared__ float sE[HIDN], sQ[HIDN], sK[HIDN], sV[HIDN];
    __shared__ float sG[NHD][2];
    int i = blockIdx.x, t = threadIdx.x;
    // blocks 0..127: also emit W2^T in bf16, row n=i, col k=t: w2bf[n][k]=aw2[k][n]
    if (i < HIDN) w2bf[(size_t)i * HIDN + t] = (unsigned short)f2bf(aw2[t * HIDN + i]);
    sE[t] = ef[i * HIDN + t];
    __syncthreads();
    float aq = 0.f, ak = 0.f, av = 0.f;
#pragma unroll 8
    for (int c = 0; c < HIDN; c++) {
        float e = sE[c];
        aq += e * wq[c * HIDN + t];
        ak += e * wk[c * HIDN + t];
        av += e * wv[c * HIDN + t];
    }
    v[i * HIDN + t] = av;
    sQ[t] = aq; sK[t] = ak; sV[t] = av;
    __syncthreads();
    for (int h = 0; h < NHD; h++) {
        float accq = 0.f, acck = 0.f;
#pragma unroll
        for (int d = 0; d < DHD; d++) {
            accq += sQ[h * DHD + d] * aw1[d * HIDN + t];
            acck += sK[h * DHD + d] * aw1[(DHD + d) * HIDN + t];
        }
        Qpb[((size_t)h * N + i) * HIDN + t] = (unsigned short)f2bf(accq);
        Kpb[((size_t)h * N + i) * HIDN + t] = (unsigned short)f2bf(acck);
        float tt = gb1[t];
#pragma unroll
        for (int d = 0; d < DHD; d++) tt += sV[h * DHD + d] * gw1[d * HIDN + t];
        float contrib = siluf(tt) * gw2[t];
        float s = wave_sum(contrib);
        if ((t & 63) == 0) sG[h][t >> 6] = s;
    }
    __syncthreads();
    if (t < NHD)
        gates[i * NHD + t] = 1.0f / (1.0f + __expf(-(sG[t][0] + sG[t][1] + gb2[0])));
}

// ---------------- K2: MFMA scores kernel ----------------
// Correct x1 math (qp added per head in phase c, from LDS QPB).
// R stored bf16 for BOTH jt tiles (32 rows x 272B) -> b-phases merged,
// c-phases merged: 2 barriers/chunk + prologue = 7 total (was 16).
// a(ch+1) overlapped into the c-region (RBF/SDD already consumed by b).
#define OFF_W2T  0            // 128 rows x 256B, XOR-swizzled = 32768
#define OFF_QPB  32768        // 8x128 bf16 = 2048
#define OFF_SDD  34816        // 32 f32 = 128
#define OFF_RBF  34944        // 32 rows x 128B, XOR-swizzled = 4096
#define OFF_R    39040        // 32 rows x 272B bf16 = 8704
#define OFF_B2   47744        // 128 f32 = 512
#define OFF_W3T  48256        // 8 x 128 f32 = 4096
#define SMEM_SZ  52352

__global__ __launch_bounds__(512, 4) void k_scores_mfma(
    const float* __restrict__ coords, const float* __restrict__ mask,
    const float* __restrict__ centers, const float* __restrict__ widths,
    const float* __restrict__ aw1, const float* __restrict__ ab1,
    const float* __restrict__ ab2,
    const float* __restrict__ aw3, const float* __restrict__ ab3,
    const unsigned short* __restrict__ Qpb, const unsigned short* __restrict__ Kpb,
    const unsigned short* __restrict__ w2bf,
    float* __restrict__ scores) {
    __shared__ __align__(16) char smem[SMEM_SZ];
    const int t = threadIdx.x;
    const int lane = t & 63;
    const int w = t >> 6;            // wave 0..7 == head
    const int l15 = lane & 15;
    const int quad = lane >> 4;
    const int i = blockIdx.y;
    const int jb = blockIdx.x * 96;

    // ---- phase 0: stage W2^T (swizzled) + QPB + b2 + w3t tables ----
    {
        const uint4* src = (const uint4*)w2bf;   // 2048 x 16B
        for (int idx = t; idx < 2048; idx += 512) {
            int row = idx >> 4, slot = idx & 15;
            *(uint4*)(smem + OFF_W2T + row * 256 + ((slot * 16) ^ ((row & 7) << 4))) = src[idx];
        }
    }
    if (t < 128) {
        ((uint4*)(smem + OFF_QPB))[t] = ((const uint4*)(Qpb + (size_t)i * NHD * HIDN))[t];
        *(float*)(smem + OFF_B2 + t * 4) = ab2[t];
    }
    for (int idx = t; idx < HIDN * NHD; idx += 512) {
        int h = idx >> 7, c = idx & 127;
        *(float*)(smem + OFF_W3T + (h * 128 + c) * 4) = aw3[c * NHD + h];
    }
    // W1r B-frags in registers: wave w covers c-tile ct=w
    const int c0 = w * 16 + l15;
    bf16x8 BW1[2];
#pragma unroll
    for (int ks = 0; ks < 2; ks++) {
        bf16x8 a;
#pragma unroll
        for (int e = 0; e < 8; e++) {
            int r = ks * 32 + quad * 8 + e;
            a[e] = f2bf(aw1[(32 + r) * HIDN + c0]);
        }
        BW1[ks] = a;
    }
    const float b1v = ab1[c0];
    const float w1dv = aw1[96 * HIDN + c0];
    const float ab3v = ab3[w];
    const float cr = centers[lane], rwd = widths[lane];
    const float cix = coords[i * 3], ciy = coords[i * 3 + 1], ciz = coords[i * 3 + 2];

    // ---- prologue: a(0) ----
    {
#pragma unroll
        for (int p = 0; p < 4; p++) {
            int j = w + p * 8;
            int jj = jb + j;
            float jx = coords[jj * 3], jy = coords[jj * 3 + 1], jz = coords[jj * 3 + 2];
            float dx = cix - jx, dy = ciy - jy, dz = ciz - jz;
            float dist = sqrtf(dx * dx + dy * dy + dz * dz) + 1e-8f;
            dist = fminf(fmaxf(dist, 1e-8f), 1e8f);
            float dd = dist - cr;
            float val = (dist <= CUTF) ? __expf(-rwd * dd * dd) : 0.0f;
            *(short*)(smem + OFF_RBF + j * 128 + ((lane * 2) ^ ((j & 7) << 4))) = f2bf(val);
        }
        if (t < 32) {
            int jj = jb + t;
            float jx = coords[jj * 3], jy = coords[jj * 3 + 1], jz = coords[jj * 3 + 2];
            float dot = fminf(fmaxf(cix * jx + ciy * jy + ciz * jz, -1e8f), 1e8f);
            *(float*)(smem + OFF_SDD + t * 4) = dot;
        }
    }
    __syncthreads();

    for (int ch = 0; ch < 3; ch++) {
        const int j0 = jb + ch * 32;
        // (b) merged: R32(bf16) = (b1 + dot*w1d) + rbf@W1r, both jt tiles
#pragma unroll
        for (int jt = 0; jt < 2; jt++) {
            int jl = jt * 16 + l15;
            int sw = (jl & 7) << 4;
            bf16x8 ra0 = *(const bf16x8*)(smem + OFF_RBF + jl * 128 + ((quad * 16) ^ sw));
            bf16x8 ra1 = *(const bf16x8*)(smem + OFF_RBF + jl * 128 + ((64 + quad * 16) ^ sw));
            floatx4 acc;
#pragma unroll
            for (int r = 0; r < 4; r++) {
                float dotv = *(const float*)(smem + OFF_SDD + (jt * 16 + quad * 4 + r) * 4);
                acc[r] = b1v + dotv * w1dv;
            }
            acc = MFMA16(ra0, BW1[0], acc);
            acc = MFMA16(ra1, BW1[1], acc);
#pragma unroll
            for (int r = 0; r < 4; r++)
                *(short*)(smem + OFF_R + (jt * 16 + quad * 4 + r) * 272 + c0 * 2) = f2bf(acc[r]);
        }
        __syncthreads();
        // (a) next chunk overlapped with (c): RBF/SDD already consumed by (b)
        if (ch < 2) {
            const int j0n = j0 + 32;
#pragma unroll
            for (int p = 0; p < 4; p++) {
                int j = w + p * 8;
                int jj = j0n + j;
                float jx = coords[jj * 3], jy = coords[jj * 3 + 1], jz = coords[jj * 3 + 2];
                float dx = cix - jx, dy = ciy - jy, dz = ciz - jz;
                float dist = sqrtf(dx * dx + dy * dy + dz * dz) + 1e-8f;
                dist = fminf(fmaxf(dist, 1e-8f), 1e8f);
                float dd = dist - cr;
                float val = (dist <= CUTF) ? __expf(-rwd * dd * dd) : 0.0f;
                *(short*)(smem + OFF_RBF + j * 128 + ((lane * 2) ^ ((j & 7) << 4))) = f2bf(val);
            }
            if (t < 32) {
                int jj = j0n + t;
                float jx = coords[jj * 3], jy = coords[jj * 3 + 1], jz = coords[jj * 3 + 2];
                float dot = fminf(fmaxf(cix * jx + ciy * jy + ciz * jz, -1e8f), 1e8f);
                *(float*)(smem + OFF_SDD + t * 4) = dot;
            }
        }
        // (c) merged: strips for both jt, head h = w
#pragma unroll
        for (int jt = 0; jt < 2; jt++) {
            const int jl = jt * 16 + l15;
            bf16x8 A[4];
#pragma unroll
            for (int f = 0; f < 4; f++) {
                const int c8 = f * 32 + quad * 8;
                bf16x8 kp = *(const bf16x8*)(Kpb + ((size_t)w * N + j0 + jl) * HIDN + c8);
                bf16x8 qp = *(const bf16x8*)(smem + OFF_QPB + (w * HIDN + c8) * 2);
                bf16x8 rr = *(const bf16x8*)(smem + OFF_R + (jt * 16 + l15) * 272 + c8 * 2);
                union { unsigned int u[4]; bf16x8 v; } uu;
#pragma unroll
                for (int e2 = 0; e2 < 4; e2++) {
                    float xa = silu_fast(bf2f(kp[2 * e2])     + bf2f(qp[2 * e2])     + bf2f(rr[2 * e2]));
                    float xb = silu_fast(bf2f(kp[2 * e2 + 1]) + bf2f(qp[2 * e2 + 1]) + bf2f(rr[2 * e2 + 1]));
                    uu.u[e2] = cvt_pk_bf16(xa, xb);
                }
                A[f] = uu.v;
            }
            float part[4] = {0.f, 0.f, 0.f, 0.f};
#pragma unroll 2
            for (int ct = 0; ct < 8; ct++) {
                const int rw2 = ct * 16 + l15;
                const char* wb = smem + OFF_W2T + rw2 * 256;
                const int sw = (rw2 & 7) << 4;
                bf16x8 b0 = *(const bf16x8*)(wb + ((quad * 16) ^ sw));
                bf16x8 b1 = *(const bf16x8*)(wb + ((64 + quad * 16) ^ sw));
                bf16x8 b2 = *(const bf16x8*)(wb + ((128 + quad * 16) ^ sw));
                bf16x8 b3 = *(const bf16x8*)(wb + ((192 + quad * 16) ^ sw));
                float bb = *(const float*)(smem + OFF_B2 + rw2 * 4);
                float ww = *(const float*)(smem + OFF_W3T + (w * 128 + rw2) * 4);
                floatx4 acc = {bb, bb, bb, bb};
                acc = MFMA16(A[0], b0, acc);
                acc = MFMA16(A[1], b1, acc);
                acc = MFMA16(A[2], b2, acc);
                acc = MFMA16(A[3], b3, acc);
#pragma unroll
                for (int r = 0; r < 4; r++)
                    part[r] += silu_fast(acc[r]) * ww;
            }
#pragma unroll
            for (int off = 1; off < 16; off <<= 1) {
#pragma unroll
                for (int r = 0; r < 4; r++)
                    part[r] += __shfl_xor(part[r], off, 64);
            }
            if (l15 == 0) {
                const int jo = j0 + jt * 16 + quad * 4;
                float4 mv = *(const float4*)(mask + (size_t)i * N + jo);
                float4 sv;
                sv.x = fminf(fmaxf(part[0] + ab3v + mv.x, -1e9f), 1e9f);
                sv.y = fminf(fmaxf(part[1] + ab3v + mv.y, -1e9f), 1e9f);
                sv.z = fminf(fmaxf(part[2] + ab3v + mv.z, -1e9f), 1e9f);
                sv.w = fminf(fmaxf(part[3] + ab3v + mv.w, -1e9f), 1e9f);
                *(float4*)(scores + ((size_t)w * N + i) * N + jo) = sv;
            }
        }
        __syncthreads();
    }
}

// K3: softmax + attn@V + coords out + fused (upd@wo + LN) epilogue.
__global__ __launch_bounds__(256) void k_attn2(
    const float* __restrict__ scores, const float* __restrict__ v,
    const float* __restrict__ gates, const float* __restrict__ coords,
    const float* __restrict__ ef, const float* __restrict__ wo,
    const float* __restrict__ bo, const float* __restrict__ lng,
    const float* __restrict__ lnb, float* __restrict__ out) {
    __shared__ float sA[4][N];
    __shared__ float sCrd[N * 3];
    __shared__ float sC[NHD][3];
    __shared__ float sUpd[HIDN];
    __shared__ float sY[HIDN];
    __shared__ float sR2[2];
    int i = blockIdx.x, t = threadIdx.x, w = t >> 6, lane = t & 63;
    for (int idx = t; idx < N * 3; idx += 256) sCrd[idx] = coords[idx];
    float cix = coords[i * 3], ciy = coords[i * 3 + 1], ciz = coords[i * 3 + 2];
    __syncthreads();
    for (int hh = 0; hh < 2; hh++) {
        int h = hh * 4 + w;
        const float* srow = scores + ((size_t)h * N + i) * N;
        float s[6];
#pragma unroll
        for (int p = 0; p < 6; p++) s[p] = srow[lane + 64 * p];
        float m = s[0];
#pragma unroll
        for (int p = 1; p < 6; p++) m = fmaxf(m, s[p]);
        for (int off = 1; off < 64; off <<= 1) m = fmaxf(m, __shfl_xor(m, off, 64));
        float e[6], sum = 0.f;
#pragma unroll
        for (int p = 0; p < 6; p++) { e[p] = __expf(s[p] - m); sum += e[p]; }
        for (int off = 1; off < 64; off <<= 1) sum += __shfl_xor(sum, off, 64);
        float inv = 1.0f / sum;
#pragma unroll
        for (int p = 0; p < 6; p++) sA[w][lane + 64 * p] = e[p] * inv;
        __syncthreads();
        // feats: d4 = lane&3 (float4 of dims), grp = lane>>2
        int d4 = lane & 3, grp = lane >> 2;
        float4 f4 = {0.f, 0.f, 0.f, 0.f};
        for (int j = grp; j < N; j += 16) {
            float a = sA[w][j];
            float4 vv = *(const float4*)(v + j * HIDN + h * DHD + d4 * 4);
            f4.x += a * vv.x; f4.y += a * vv.y; f4.z += a * vv.z; f4.w += a * vv.w;
        }
#pragma unroll
        for (int off = 4; off < 64; off <<= 1) {
            f4.x += __shfl_xor(f4.x, off, 64);
            f4.y += __shfl_xor(f4.y, off, 64);
            f4.z += __shfl_xor(f4.z, off, 64);
            f4.w += __shfl_xor(f4.w, off, 64);
        }
        if (lane < 4) *(float4*)(&sUpd[h * DHD + lane * 4]) = f4;
        // coords partial
        float cx = 0.f, cy = 0.f, cz = 0.f;
#pragma unroll
        for (int p = 0; p < 6; p++) {
            int j = lane + 64 * p;
            float a = sA[w][j];
            cx += a * (cix - sCrd[j * 3]);
            cy += a * (ciy - sCrd[j * 3 + 1]);
            cz += a * (ciz - sCrd[j * 3 + 2]);
        }
        for (int off = 1; off < 64; off <<= 1) {
            cx += __shfl_xor(cx, off, 64);
            cy += __shfl_xor(cy, off, 64);
            cz += __shfl_xor(cz, off, 64);
        }
        if (lane == 0) {
            float g = gates[i * NHD + h] * (1.0f / NHD);
            sC[h][0] = g * cx; sC[h][1] = g * cy; sC[h][2] = g * cz;
        }
        __syncthreads();
    }
    if (t < 3) {
        float acc = coords[i * 3 + t];
#pragma unroll
        for (int h = 0; h < NHD; h++) acc += sC[h][t];
        out[N * HIDN + i * 3 + t] = acc;
    }
    // fused k_out: y = ef + sUpd@wo + bo, LayerNorm.
    // Dot split: group g (t>>7) handles cp = g*64..g*64+63; combine via sY.
    int c = t & 127, g = t >> 7;
    float y = g ? 0.f : (ef[i * HIDN + c] + bo[c]);
#pragma unroll 8
    for (int cp = 0; cp < 64; cp++) {
        int cc = g * 64 + cp;
        y += sUpd[cc] * wo[cc * HIDN + c];
    }
    if (g) sY[c] = y;
    __syncthreads();
    if (!g) y += sY[c];
    float ssum = wave_sum(y);
    if (t < 128 && (t & 63) == 0) sR2[t >> 6] = ssum;
    __syncthreads();
    float mu = (sR2[0] + sR2[1]) * (1.0f / HIDN);
    __syncthreads();
    float dv = y - mu;
    float s2 = wave_sum(dv * dv);
    if (t < 128 && (t & 63) == 0) sR2[t >> 6] = s2;
    __syncthreads();
    float var = (sR2[0] + sR2[1]) * (1.0f / HIDN);
    if (t < 128) out[i * HIDN + c] = dv * rsqrtf(var + 1e-5f) * lng[c] + lnb[c];
}

extern "C" void kernel_launch(void* const* d_in, const int* in_sizes, int n_in,
                              void* d_out, int out_size, void* d_ws, size_t ws_size,
                              hipStream_t stream) {
    const float* ef      = (const float*)d_in[0];
    const float* coords  = (const float*)d_in[1];
    const float* mask    = (const float*)d_in[2];
    const float* wq      = (const float*)d_in[3];
    const float* wk      = (const float*)d_in[4];
    const float* wv      = (const float*)d_in[5];
    const float* centers = (const float*)d_in[6];
    const float* widths  = (const float*)d_in[7];
    const float* aw1     = (const float*)d_in[8];
    const float* ab1     = (const float*)d_in[9];
    const float* aw2     = (const float*)d_in[10];
    const float* ab2     = (const float*)d_in[11];
    const float* aw3     = (const float*)d_in[12];
    const float* ab3     = (const float*)d_in[13];
    const float* gw1     = (const float*)d_in[14];
    const float* gb1     = (const float*)d_in[15];
    const float* gw2     = (const float*)d_in[16];
    const float* gb2     = (const float*)d_in[17];
    const float* wo      = (const float*)d_in[18];
    const float* bo      = (const float*)d_in[19];
    const float* lng     = (const float*)d_in[20];
    const float* lnb     = (const float*)d_in[21];
    float* ws = (float*)d_ws;
    float* v      = ws + WS_V;
    unsigned short* Qpb = (unsigned short*)(ws + WS_QPB);
    unsigned short* Kpb = (unsigned short*)(ws + WS_KPB);
    float* gates  = ws + WS_GATE;
    float* scores = ws + WS_SCORES;
    unsigned short* w2bf = (unsigned short*)(ws + WS_W2BF);
    float* out = (float*)d_out;

    k_pre<<<N, 128, 0, stream>>>(ef, wq, wk, wv, aw1, aw2, gw1, gb1, gw2, gb2, v, Qpb, Kpb, gates, w2bf);
    k_scores_mfma<<<dim3(4, N), 512, 0, stream>>>(
        coords, mask, centers, widths, aw1, ab1, ab2, aw3, ab3, Qpb, Kpb, w2bf, scores);
    k_attn2<<<N, 256, 0, stream>>>(scores, v, gates, coords, ef, wo, bo, lng, lnb, out);
}

// Round 11
// 249.248 us; speedup vs baseline: 1.0239x; 1.0239x over previous
//
#include <hip/hip_runtime.h>
#include <hip/hip_bf16.h>

#define N 384
#define HIDN 128
#define NHD 8
#define DHD 16
#define NRB 64
#define CUTF 10.0f

// ws layout (float slots)
#define WS_V 0
#define WS_QPB (WS_V + N*HIDN)                 // bf16 buffer: head-major [h][n][c]
#define WS_KPB (WS_QPB + N*NHD*HIDN/2)        // bf16 buffer: head-major [h][n][c]
#define WS_GATE (WS_KPB + N*NHD*HIDN/2)
#define WS_UPD (WS_GATE + N*NHD)
#define WS_SCORES (WS_UPD + N*HIDN)
#define WS_W2BF (WS_SCORES + NHD*N*N)         // bf16 buffer: 128*128 shorts (W2^T)

typedef short bf16x8 __attribute__((ext_vector_type(8)));
typedef float floatx4 __attribute__((ext_vector_type(4)));
#define MFMA16(a, b, c) __builtin_amdgcn_mfma_f32_16x16x32_bf16(a, b, c, 0, 0, 0)

__device__ __forceinline__ float siluf(float x) { return x / (1.0f + __expf(-x)); }
__device__ __forceinline__ float silu_fast(float x) {
    return x * __builtin_amdgcn_rcpf(1.0f + __expf(-x));
}
__device__ __forceinline__ short f2bf(float f) {
    unsigned int b = __float_as_uint(f);
    unsigned int r = (b + 0x7fffu + ((b >> 16) & 1u)) >> 16;
    return (short)r;
}
__device__ __forceinline__ float bf2f(short s) {
    return __uint_as_float(((unsigned int)(unsigned short)s) << 16);
}
// packed f32x2 -> bf16x2 (RNE), 1 instr instead of 2x5
__device__ __forceinline__ unsigned int cvt_pk_bf16(float lo, float hi) {
    unsigned int r;
    asm("v_cvt_pk_bf16_f32 %0, %1, %2" : "=v"(r) : "v"(lo), "v"(hi));
    return r;
}
__device__ __forceinline__ float wave_sum(float v) {
    for (int o = 32; o; o >>= 1) v += __shfl_down(v, o, 64);
    return v;
}

// K1: fused qkv + Qp/Kp(bf16, head-major) + gates + W2^T bf16 pre-transpose
__global__ __launch_bounds__(128) void k_pre(const float* __restrict__ ef,
    const float* __restrict__ wq, const float* __restrict__ wk, const float* __restrict__ wv,
    const float* __restrict__ aw1, const float* __restrict__ aw2,
    const float* __restrict__ gw1, const float* __restrict__ gb1,
    const float* __restrict__ gw2, const float* __restrict__ gb2,
    float* __restrict__ v, unsigned short* __restrict__ Qpb,
    unsigned short* __restrict__ Kpb, float* __restrict__ gates,
    unsigned short* __restrict__ w2bf) {
    __shared__ float sE[HIDN], sQ[HIDN], sK[HIDN], sV[HIDN];
    __shared__ float sG[NHD][2];
    int i = blockIdx.x, t = threadIdx.x;
    // blocks 0..127: also emit W2^T in bf16, row n=i, col k=t: w2bf[n][k]=aw2[k][n]
    if (i < HIDN) w2bf[(size_t)i * HIDN + t] = (unsigned short)f2bf(aw2[t * HIDN + i]);
    sE[t] = ef[i * HIDN + t];
    __syncthreads();
    float aq = 0.f, ak = 0.f, av = 0.f;
#pragma unroll 8
    for (int c = 0; c < HIDN; c++) {
        float e = sE[c];
        aq += e * wq[c * HIDN + t];
        ak += e * wk[c * HIDN + t];
        av += e * wv[c * HIDN + t];
    }
    v[i * HIDN + t] = av;
    sQ[t] = aq; sK[t] = ak; sV[t] = av;
    __syncthreads();
    for (int h = 0; h < NHD; h++) {
        float accq = 0.f, acck = 0.f;
#pragma unroll
        for (int d = 0; d < DHD; d++) {
            accq += sQ[h * DHD + d] * aw1[d * HIDN + t];
            acck += sK[h * DHD + d] * aw1[(DHD + d) * HIDN + t];
        }
        Qpb[((size_t)h * N + i) * HIDN + t] = (unsigned short)f2bf(accq);
        Kpb[((size_t)h * N + i) * HIDN + t] = (unsigned short)f2bf(acck);
        float tt = gb1[t];
#pragma unroll
        for (int d = 0; d < DHD; d++) tt += sV[h * DHD + d] * gw1[d * HIDN + t];
        float contrib = siluf(tt) * gw2[t];
        float s = wave_sum(contrib);
        if ((t & 63) == 0) sG[h][t >> 6] = s;
    }
    __syncthreads();
    if (t < NHD)
        gates[i * NHD + t] = 1.0f / (1.0f + __expf(-(sG[t][0] + sG[t][1] + gb2[0])));
}

// ---------------- K2: MFMA scores kernel ----------------
// Round-8 proven schedule (VGPR 64, no spill, 3 blocks/CU, jt-split,
// f32 R 16 rows) with f32 b2/w3t tables (precision restore).
#define OFF_W2T  0            // 128 rows x 256B, XOR-swizzled = 32768
#define OFF_QPB  32768        // 8x128 bf16 = 2048
#define OFF_SDD  34816        // 32 f32 = 128
#define OFF_RBF  34944        // 32 rows x 128B, XOR-swizzled = 4096
#define OFF_R    39040        // 16 rows x 528B f32 = 8448
#define OFF_B2   47488        // 128 f32 = 512
#define OFF_W3T  48000        // 8 x 128 f32 = 4096
#define SMEM_SZ  52096

__global__ __launch_bounds__(512, 4) void k_scores_mfma(
    const float* __restrict__ coords, const float* __restrict__ mask,
    const float* __restrict__ centers, const float* __restrict__ widths,
    const float* __restrict__ aw1, const float* __restrict__ ab1,
    const float* __restrict__ ab2,
    const float* __restrict__ aw3, const float* __restrict__ ab3,
    const unsigned short* __restrict__ Qpb, const unsigned short* __restrict__ Kpb,
    const unsigned short* __restrict__ w2bf,
    float* __restrict__ scores) {
    __shared__ __align__(16) char smem[SMEM_SZ];
    const int t = threadIdx.x;
    const int lane = t & 63;
    const int w = t >> 6;            // wave 0..7 == head
    const int l15 = lane & 15;
    const int quad = lane >> 4;
    const int i = blockIdx.y;
    const int jb = blockIdx.x * 96;

    // ---- phase 0: stage W2^T (swizzled) + QPB + b2 + w3t tables ----
    {
        const uint4* src = (const uint4*)w2bf;   // 2048 x 16B
        for (int idx = t; idx < 2048; idx += 512) {
            int row = idx >> 4, slot = idx & 15;
            *(uint4*)(smem + OFF_W2T + row * 256 + ((slot * 16) ^ ((row & 7) << 4))) = src[idx];
        }
    }
    if (t < 128) {
        ((uint4*)(smem + OFF_QPB))[t] = ((const uint4*)(Qpb + (size_t)i * NHD * HIDN))[t];
        *(float*)(smem + OFF_B2 + t * 4) = ab2[t];
    }
    for (int idx = t; idx < HIDN * NHD; idx += 512) {
        int h = idx >> 7, c = idx & 127;
        *(float*)(smem + OFF_W3T + (h * 128 + c) * 4) = aw3[c * NHD + h];
    }
    // W1r B-frags in registers: wave w covers c-tile ct=w
    const int c0 = w * 16 + l15;
    bf16x8 BW1[2];
#pragma unroll
    for (int ks = 0; ks < 2; ks++) {
        bf16x8 a;
#pragma unroll
        for (int e = 0; e < 8; e++) {
            int r = ks * 32 + quad * 8 + e;
            a[e] = f2bf(aw1[(32 + r) * HIDN + c0]);
        }
        BW1[ks] = a;
    }
    const float b1v = ab1[c0];
    const float w1dv = aw1[96 * HIDN + c0];
    const float ab3v = ab3[w];
    const float cr = centers[lane], rwd = widths[lane];
    const float cix = coords[i * 3], ciy = coords[i * 3 + 1], ciz = coords[i * 3 + 2];
    __syncthreads();

    for (int ch = 0; ch < 3; ch++) {
        const int j0 = jb + ch * 32;
        // (a) rbf + dot. r = lane, j = w + p*8
        {
#pragma unroll
            for (int p = 0; p < 4; p++) {
                int j = w + p * 8;
                int jj = j0 + j;
                float jx = coords[jj * 3], jy = coords[jj * 3 + 1], jz = coords[jj * 3 + 2];
                float dx = cix - jx, dy = ciy - jy, dz = ciz - jz;
                float dist = sqrtf(dx * dx + dy * dy + dz * dz) + 1e-8f;
                dist = fminf(fmaxf(dist, 1e-8f), 1e8f);
                float dd = dist - cr;
                float val = (dist <= CUTF) ? __expf(-rwd * dd * dd) : 0.0f;
                *(short*)(smem + OFF_RBF + j * 128 + ((lane * 2) ^ ((j & 7) << 4))) = f2bf(val);
            }
            if (t < 32) {
                int jj = j0 + t;
                float jx = coords[jj * 3], jy = coords[jj * 3 + 1], jz = coords[jj * 3 + 2];
                float dot = fminf(fmaxf(cix * jx + ciy * jy + ciz * jz, -1e8f), 1e8f);
                *(float*)(smem + OFF_SDD + t * 4) = dot;
            }
        }
        __syncthreads();
#pragma unroll
        for (int jt = 0; jt < 2; jt++) {
            // (b) R16 = (b1 + dot*w1d) + rbf@W1r for this jt's 16 rows
            {
                int jl = jt * 16 + l15;
                int sw = (jl & 7) << 4;
                bf16x8 ra0 = *(const bf16x8*)(smem + OFF_RBF + jl * 128 + ((quad * 16) ^ sw));
                bf16x8 ra1 = *(const bf16x8*)(smem + OFF_RBF + jl * 128 + ((64 + quad * 16) ^ sw));
                floatx4 acc;
#pragma unroll
                for (int r = 0; r < 4; r++) {
                    float dotv = *(const float*)(smem + OFF_SDD + (jt * 16 + quad * 4 + r) * 4);
                    acc[r] = b1v + dotv * w1dv;
                }
                acc = MFMA16(ra0, BW1[0], acc);
                acc = MFMA16(ra1, BW1[1], acc);
#pragma unroll
                for (int r = 0; r < 4; r++)
                    *(float*)(smem + OFF_R + (quad * 4 + r) * 528 + c0 * 4) = acc[r];
            }
            __syncthreads();
            // (c) strips for this jt: head h = w
            {
                const int jr = j0 + jt * 16 + l15;   // Kpb row
                bf16x8 A[4];
#pragma unroll
                for (int f = 0; f < 4; f++) {
                    const int c8 = f * 32 + quad * 8;
                    bf16x8 kp = *(const bf16x8*)(Kpb + ((size_t)w * N + jr) * HIDN + c8);
                    bf16x8 qp = *(const bf16x8*)(smem + OFF_QPB + (w * HIDN + c8) * 2);
                    const char* rbase = smem + OFF_R + l15 * 528 + c8 * 4;
                    float4 r0 = *(const float4*)(rbase);
                    float4 r1 = *(const float4*)(rbase + 16);
                    float xs[8] = {r0.x, r0.y, r0.z, r0.w, r1.x, r1.y, r1.z, r1.w};
                    union { unsigned int u[4]; bf16x8 v; } uu;
#pragma unroll
                    for (int e2 = 0; e2 < 4; e2++) {
                        float xa = silu_fast(bf2f(kp[2 * e2])     + bf2f(qp[2 * e2])     + xs[2 * e2]);
                        float xb = silu_fast(bf2f(kp[2 * e2 + 1]) + bf2f(qp[2 * e2 + 1]) + xs[2 * e2 + 1]);
                        uu.u[e2] = cvt_pk_bf16(xa, xb);
                    }
                    A[f] = uu.v;
                }
                float part[4] = {0.f, 0.f, 0.f, 0.f};
#pragma unroll 2
                for (int ct = 0; ct < 8; ct++) {
                    const int rw2 = ct * 16 + l15;
                    const char* wb = smem + OFF_W2T + rw2 * 256;
                    const int sw = (rw2 & 7) << 4;
                    bf16x8 b0 = *(const bf16x8*)(wb + ((quad * 16) ^ sw));
                    bf16x8 b1 = *(const bf16x8*)(wb + ((64 + quad * 16) ^ sw));
                    bf16x8 b2 = *(const bf16x8*)(wb + ((128 + quad * 16) ^ sw));
                    bf16x8 b3 = *(const bf16x8*)(wb + ((192 + quad * 16) ^ sw));
                    float bb = *(const float*)(smem + OFF_B2 + rw2 * 4);
                    float ww = *(const float*)(smem + OFF_W3T + (w * 128 + rw2) * 4);
                    floatx4 acc = {bb, bb, bb, bb};
                    acc = MFMA16(A[0], b0, acc);
                    acc = MFMA16(A[1], b1, acc);
                    acc = MFMA16(A[2], b2, acc);
                    acc = MFMA16(A[3], b3, acc);
#pragma unroll
                    for (int r = 0; r < 4; r++)
                        part[r] += silu_fast(acc[r]) * ww;
                }
#pragma unroll
                for (int off = 1; off < 16; off <<= 1) {
#pragma unroll
                    for (int r = 0; r < 4; r++)
                        part[r] += __shfl_xor(part[r], off, 64);
                }
                if (l15 == 0) {
                    const int jo = j0 + jt * 16 + quad * 4;
                    float4 mv = *(const float4*)(mask + (size_t)i * N + jo);
                    float4 sv;
                    sv.x = fminf(fmaxf(part[0] + ab3v + mv.x, -1e9f), 1e9f);
                    sv.y = fminf(fmaxf(part[1] + ab3v + mv.y, -1e9f), 1e9f);
                    sv.z = fminf(fmaxf(part[2] + ab3v + mv.z, -1e9f), 1e9f);
                    sv.w = fminf(fmaxf(part[3] + ab3v + mv.w, -1e9f), 1e9f);
                    *(float4*)(scores + ((size_t)w * N + i) * N + jo) = sv;
                }
            }
            __syncthreads();
        }
    }
}

// K3: softmax + attn@V + coords + fused LN.  512 threads, 8 waves,
// ONE head per wave (no serial hh loop).  Softmax/feats/coords are
// wave-local on sA[w] (no barriers between them).  LN dot split 4-ways
// across all 512 threads.
__global__ __launch_bounds__(512) void k_attn2(
    const float* __restrict__ scores, const float* __restrict__ v,
    const float* __restrict__ gates, const float* __restrict__ coords,
    const float* __restrict__ ef, const float* __restrict__ wo,
    const float* __restrict__ bo, const float* __restrict__ lng,
    const float* __restrict__ lnb, float* __restrict__ out) {
    __shared__ float sA[NHD][N];
    __shared__ float sCrd[N * 3];
    __shared__ float sC[NHD][3];
    __shared__ float sUpd[HIDN];
    __shared__ float sP[3][HIDN];
    __shared__ float sR2[2];
    int i = blockIdx.x, t = threadIdx.x, w = t >> 6, lane = t & 63;
    for (int idx = t; idx < N * 3; idx += 512) sCrd[idx] = coords[idx];
    float cix = coords[i * 3], ciy = coords[i * 3 + 1], ciz = coords[i * 3 + 2];
    __syncthreads();
    {
        const int h = w;
        const float* srow = scores + ((size_t)h * N + i) * N;
        float s[6];
#pragma unroll
        for (int p = 0; p < 6; p++) s[p] = srow[lane + 64 * p];
        float m = s[0];
#pragma unroll
        for (int p = 1; p < 6; p++) m = fmaxf(m, s[p]);
        for (int off = 1; off < 64; off <<= 1) m = fmaxf(m, __shfl_xor(m, off, 64));
        float e[6], sum = 0.f;
#pragma unroll
        for (int p = 0; p < 6; p++) { e[p] = __expf(s[p] - m); sum += e[p]; }
        for (int off = 1; off < 64; off <<= 1) sum += __shfl_xor(sum, off, 64);
        float inv = 1.0f / sum;
#pragma unroll
        for (int p = 0; p < 6; p++) sA[w][lane + 64 * p] = e[p] * inv;
        // feats (wave-local sA): d4 = lane&3, grp = lane>>2
        int d4 = lane & 3, grp = lane >> 2;
        float4 f4 = {0.f, 0.f, 0.f, 0.f};
        for (int j = grp; j < N; j += 16) {
            float a = sA[w][j];
            float4 vv = *(const float4*)(v + j * HIDN + h * DHD + d4 * 4);
            f4.x += a * vv.x; f4.y += a * vv.y; f4.z += a * vv.z; f4.w += a * vv.w;
        }
#pragma unroll
        for (int off = 4; off < 64; off <<= 1) {
            f4.x += __shfl_xor(f4.x, off, 64);
            f4.y += __shfl_xor(f4.y, off, 64);
            f4.z += __shfl_xor(f4.z, off, 64);
            f4.w += __shfl_xor(f4.w, off, 64);
        }
        if (lane < 4) *(float4*)(&sUpd[h * DHD + lane * 4]) = f4;
        // coords partial (wave-local)
        float cx = 0.f, cy = 0.f, cz = 0.f;
#pragma unroll
        for (int p = 0; p < 6; p++) {
            int j = lane + 64 * p;
            float a = sA[w][j];
            cx += a * (cix - sCrd[j * 3]);
            cy += a * (ciy - sCrd[j * 3 + 1]);
            cz += a * (ciz - sCrd[j * 3 + 2]);
        }
        for (int off = 1; off < 64; off <<= 1) {
            cx += __shfl_xor(cx, off, 64);
            cy += __shfl_xor(cy, off, 64);
            cz += __shfl_xor(cz, off, 64);
        }
        if (lane == 0) {
            float g = gates[i * NHD + h] * (1.0f / NHD);
            sC[h][0] = g * cx; sC[h][1] = g * cy; sC[h][2] = g * cz;
        }
    }
    __syncthreads();
    if (t < 3) {
        float acc = coords[i * 3 + t];
#pragma unroll
        for (int h = 0; h < NHD; h++) acc += sC[h][t];
        out[N * HIDN + i * 3 + t] = acc;
    }
    // fused LN: y = ef + sUpd@wo + bo.  Dot split 4 ways: group g = t>>7
    // handles cp = g*32..g*32+31; groups 1-3 park partials in sP.
    int c = t & 127, g = t >> 7;
    float y = (g == 0) ? (ef[i * HIDN + c] + bo[c]) : 0.f;
#pragma unroll 8
    for (int cp = 0; cp < 32; cp++) {
        int cc = g * 32 + cp;
        y += sUpd[cc] * wo[cc * HIDN + c];
    }
    if (g > 0) sP[g - 1][c] = y;
    __syncthreads();
    if (g == 0) y += sP[0][c] + sP[1][c] + sP[2][c];
    float ssum = wave_sum(y);
    if (t < 128 && (t & 63) == 0) sR2[t >> 6] = ssum;
    __syncthreads();
    float mu = (sR2[0] + sR2[1]) * (1.0f / HIDN);
    __syncthreads();
    float dv = y - mu;
    float s2 = wave_sum(dv * dv);
    if (t < 128 && (t & 63) == 0) sR2[t >> 6] = s2;
    __syncthreads();
    float var = (sR2[0] + sR2[1]) * (1.0f / HIDN);
    if (t < 128) out[i * HIDN + c] = dv * rsqrtf(var + 1e-5f) * lng[c] + lnb[c];
}

extern "C" void kernel_launch(void* const* d_in, const int* in_sizes, int n_in,
                              void* d_out, int out_size, void* d_ws, size_t ws_size,
                              hipStream_t stream) {
    const float* ef      = (const float*)d_in[0];
    const float* coords  = (const float*)d_in[1];
    const float* mask    = (const float*)d_in[2];
    const float* wq      = (const float*)d_in[3];
    const float* wk      = (const float*)d_in[4];
    const float* wv      = (const float*)d_in[5];
    const float* centers = (const float*)d_in[6];
    const float* widths  = (const float*)d_in[7];
    const float* aw1     = (const float*)d_in[8];
    const float* ab1     = (const float*)d_in[9];
    const float* aw2     = (const float*)d_in[10];
    const float* ab2     = (const float*)d_in[11];
    const float* aw3     = (const float*)d_in[12];
    const float* ab3     = (const float*)d_in[13];
    const float* gw1     = (const float*)d_in[14];
    const float* gb1     = (const float*)d_in[15];
    const float* gw2     = (const float*)d_in[16];
    const float* gb2     = (const float*)d_in[17];
    const float* wo      = (const float*)d_in[18];
    const float* bo      = (const float*)d_in[19];
    const float* lng     = (const float*)d_in[20];
    const float* lnb     = (const float*)d_in[21];
    float* ws = (float*)d_ws;
    float* v      = ws + WS_V;
    unsigned short* Qpb = (unsigned short*)(ws + WS_QPB);
    unsigned short* Kpb = (unsigned short*)(ws + WS_KPB);
    float* gates  = ws + WS_GATE;
    float* scores = ws + WS_SCORES;
    unsigned short* w2bf = (unsigned short*)(ws + WS_W2BF);
    float* out = (float*)d_out;

    k_pre<<<N, 128, 0, stream>>>(ef, wq, wk, wv, aw1, aw2, gw1, gb1, gw2, gb2, v, Qpb, Kpb, gates, w2bf);
    k_scores_mfma<<<dim3(4, N), 512, 0, stream>>>(
        coords, mask, centers, widths, aw1, ab1, ab2, aw3, ab3, Qpb, Kpb, w2bf, scores);
    k_attn2<<<N, 512, 0, stream>>>(scores, v, gates, coords, ef, wo, bo, lng, lnb, out);
}

// Round 12
// 241.572 us; speedup vs baseline: 1.0565x; 1.0318x over previous
//
#include <hip/hip_runtime.h>
#include <hip/hip_bf16.h>

#define N 384
#define HIDN 128
#define NHD 8
#define DHD 16
#define NRB 64
#define CUTF 10.0f
#define LOG2E 1.44269504f
#define LN2   0.69314718f

// ws layout (float slots)
#define WS_V 0
#define WS_QPB (WS_V + N*HIDN)                 // bf16 buffer: head-major [h][n][c], pre-scaled x log2e
#define WS_KPB (WS_QPB + N*NHD*HIDN/2)        // bf16 buffer: head-major [h][n][c], pre-scaled x log2e
#define WS_GATE (WS_KPB + N*NHD*HIDN/2)
#define WS_UPD (WS_GATE + N*NHD)
#define WS_SCORES (WS_UPD + N*HIDN)
#define WS_W2BF (WS_SCORES + NHD*N*N)         // bf16 buffer: 128*128 shorts (W2^T, unscaled)

typedef short bf16x8 __attribute__((ext_vector_type(8)));
typedef float floatx4 __attribute__((ext_vector_type(4)));
#define MFMA16(a, b, c) __builtin_amdgcn_mfma_f32_16x16x32_bf16(a, b, c, 0, 0, 0)

__device__ __forceinline__ float siluf(float x) { return x / (1.0f + __expf(-x)); }
// silu in base-2 domain: x' = log2e * t.  Returns x' * sigmoid(t) = log2e * silu(t).
__device__ __forceinline__ float silu2_fast(float x) {
    return x * __builtin_amdgcn_rcpf(1.0f + __builtin_amdgcn_exp2f(-x));
}
__device__ __forceinline__ short f2bf(float f) {
    unsigned int b = __float_as_uint(f);
    unsigned int r = (b + 0x7fffu + ((b >> 16) & 1u)) >> 16;
    return (short)r;
}
__device__ __forceinline__ float bf2f(short s) {
    return __uint_as_float(((unsigned int)(unsigned short)s) << 16);
}
// packed f32x2 -> bf16x2 (RNE), 1 instr instead of 2x5
__device__ __forceinline__ unsigned int cvt_pk_bf16(float lo, float hi) {
    unsigned int r;
    asm("v_cvt_pk_bf16_f32 %0, %1, %2" : "=v"(r) : "v"(lo), "v"(hi));
    return r;
}
__device__ __forceinline__ float wave_sum(float v) {
    for (int o = 32; o; o >>= 1) v += __shfl_down(v, o, 64);
    return v;
}

// K1: fused qkv + Qp/Kp(bf16, head-major, x log2e) + gates + W2^T bf16 pre-transpose
__global__ __launch_bounds__(128) void k_pre(const float* __restrict__ ef,
    const float* __restrict__ wq, const float* __restrict__ wk, const float* __restrict__ wv,
    const float* __restrict__ aw1, const float* __restrict__ aw2,
    const float* __restrict__ gw1, const float* __restrict__ gb1,
    const float* __restrict__ gw2, const float* __restrict__ gb2,
    float* __restrict__ v, unsigned short* __restrict__ Qpb,
    unsigned short* __restrict__ Kpb, float* __restrict__ gates,
    unsigned short* __restrict__ w2bf) {
    __shared__ float sE[HIDN], sQ[HIDN], sK[HIDN], sV[HIDN];
    __shared__ float sG[NHD][2];
    int i = blockIdx.x, t = threadIdx.x;
    // blocks 0..127: also emit W2^T in bf16, row n=i, col k=t: w2bf[n][k]=aw2[k][n]
    if (i < HIDN) w2bf[(size_t)i * HIDN + t] = (unsigned short)f2bf(aw2[t * HIDN + i]);
    sE[t] = ef[i * HIDN + t];
    __syncthreads();
    float aq = 0.f, ak = 0.f, av = 0.f;
#pragma unroll 8
    for (int c = 0; c < HIDN; c++) {
        float e = sE[c];
        aq += e * wq[c * HIDN + t];
        ak += e * wk[c * HIDN + t];
        av += e * wv[c * HIDN + t];
    }
    v[i * HIDN + t] = av;
    sQ[t] = aq; sK[t] = ak; sV[t] = av;
    __syncthreads();
    for (int h = 0; h < NHD; h++) {
        float accq = 0.f, acck = 0.f;
#pragma unroll
        for (int d = 0; d < DHD; d++) {
            accq += sQ[h * DHD + d] * aw1[d * HIDN + t];
            acck += sK[h * DHD + d] * aw1[(DHD + d) * HIDN + t];
        }
        Qpb[((size_t)h * N + i) * HIDN + t] = (unsigned short)f2bf(accq * LOG2E);
        Kpb[((size_t)h * N + i) * HIDN + t] = (unsigned short)f2bf(acck * LOG2E);
        float tt = gb1[t];
#pragma unroll
        for (int d = 0; d < DHD; d++) tt += sV[h * DHD + d] * gw1[d * HIDN + t];
        float contrib = siluf(tt) * gw2[t];
        float s = wave_sum(contrib);
        if ((t & 63) == 0) sG[h][t >> 6] = s;
    }
    __syncthreads();
    if (t < NHD)
        gates[i * NHD + t] = 1.0f / (1.0f + __expf(-(sG[t][0] + sG[t][1] + gb2[0])));
}

// ---------------- K2: MFMA scores kernel ----------------
// Round-11 proven schedule (VGPR 64, no spill, 3 blocks/CU, jt-split,
// f32 R 16 rows).  log2e pre-folded into Qp/Kp/W1r/b1/w1d/b2 so every
// silu is base-2 (exp2 with free neg modifier, no mul): silu drops
// 5 -> 4 instrs.  W2 stays raw; w3 pre-scaled by ln2 restores scores.
#define OFF_W2T  0            // 128 rows x 256B, XOR-swizzled = 32768
#define OFF_QPB  32768        // 8x128 bf16 = 2048
#define OFF_SDD  34816        // 32 f32 = 128
#define OFF_RBF  34944        // 32 rows x 128B, XOR-swizzled = 4096
#define OFF_R    39040        // 16 rows x 528B f32 = 8448
#define OFF_B2   47488        // 128 f32 (x log2e) = 512
#define OFF_W3T  48000        // 8 x 128 f32 (x ln2) = 4096
#define SMEM_SZ  52096

__global__ __launch_bounds__(512, 4) void k_scores_mfma(
    const float* __restrict__ coords, const float* __restrict__ mask,
    const float* __restrict__ centers, const float* __restrict__ widths,
    const float* __restrict__ aw1, const float* __restrict__ ab1,
    const float* __restrict__ ab2,
    const float* __restrict__ aw3, const float* __restrict__ ab3,
    const unsigned short* __restrict__ Qpb, const unsigned short* __restrict__ Kpb,
    const unsigned short* __restrict__ w2bf,
    float* __restrict__ scores) {
    __shared__ __align__(16) char smem[SMEM_SZ];
    const int t = threadIdx.x;
    const int lane = t & 63;
    const int w = t >> 6;            // wave 0..7 == head
    const int l15 = lane & 15;
    const int quad = lane >> 4;
    const int i = blockIdx.y;
    const int jb = blockIdx.x * 96;

    // ---- phase 0: stage W2^T (swizzled) + QPB + b2 + w3t tables ----
    {
        const uint4* src = (const uint4*)w2bf;   // 2048 x 16B
        for (int idx = t; idx < 2048; idx += 512) {
            int row = idx >> 4, slot = idx & 15;
            *(uint4*)(smem + OFF_W2T + row * 256 + ((slot * 16) ^ ((row & 7) << 4))) = src[idx];
        }
    }
    if (t < 128) {
        ((uint4*)(smem + OFF_QPB))[t] = ((const uint4*)(Qpb + (size_t)i * NHD * HIDN))[t];
        *(float*)(smem + OFF_B2 + t * 4) = ab2[t] * LOG2E;
    }
    for (int idx = t; idx < HIDN * NHD; idx += 512) {
        int h = idx >> 7, c = idx & 127;
        *(float*)(smem + OFF_W3T + (h * 128 + c) * 4) = aw3[c * NHD + h] * LN2;
    }
    // W1r B-frags in registers (x log2e): wave w covers c-tile ct=w
    const int c0 = w * 16 + l15;
    bf16x8 BW1[2];
#pragma unroll
    for (int ks = 0; ks < 2; ks++) {
        bf16x8 a;
#pragma unroll
        for (int e = 0; e < 8; e++) {
            int r = ks * 32 + quad * 8 + e;
            a[e] = f2bf(aw1[(32 + r) * HIDN + c0] * LOG2E);
        }
        BW1[ks] = a;
    }
    const float b1v = ab1[c0] * LOG2E;
    const float w1dv = aw1[96 * HIDN + c0] * LOG2E;
    const float ab3v = ab3[w];
    const float cr = centers[lane];
    const float rwd = widths[lane] * LOG2E;   // exp(-w d^2) = exp2(-(w log2e) d^2)
    const float cix = coords[i * 3], ciy = coords[i * 3 + 1], ciz = coords[i * 3 + 2];
    __syncthreads();

    for (int ch = 0; ch < 3; ch++) {
        const int j0 = jb + ch * 32;
        // (a) rbf + dot. r = lane, j = w + p*8.  rbf stored TRUE (unscaled).
        {
#pragma unroll
            for (int p = 0; p < 4; p++) {
                int j = w + p * 8;
                int jj = j0 + j;
                float jx = coords[jj * 3], jy = coords[jj * 3 + 1], jz = coords[jj * 3 + 2];
                float dx = cix - jx, dy = ciy - jy, dz = ciz - jz;
                float dist = sqrtf(dx * dx + dy * dy + dz * dz) + 1e-8f;
                dist = fminf(fmaxf(dist, 1e-8f), 1e8f);
                float dd = dist - cr;
                float val = (dist <= CUTF) ? __builtin_amdgcn_exp2f(-rwd * dd * dd) : 0.0f;
                *(short*)(smem + OFF_RBF + j * 128 + ((lane * 2) ^ ((j & 7) << 4))) = f2bf(val);
            }
            if (t < 32) {
                int jj = j0 + t;
                float jx = coords[jj * 3], jy = coords[jj * 3 + 1], jz = coords[jj * 3 + 2];
                float dot = fminf(fmaxf(cix * jx + ciy * jy + ciz * jz, -1e8f), 1e8f);
                *(float*)(smem + OFF_SDD + t * 4) = dot;
            }
        }
        __syncthreads();
#pragma unroll
        for (int jt = 0; jt < 2; jt++) {
            // (b) R16 = log2e*(b1 + dot*w1d + rbf@W1r) for this jt's 16 rows
            {
                int jl = jt * 16 + l15;
                int sw = (jl & 7) << 4;
                bf16x8 ra0 = *(const bf16x8*)(smem + OFF_RBF + jl * 128 + ((quad * 16) ^ sw));
                bf16x8 ra1 = *(const bf16x8*)(smem + OFF_RBF + jl * 128 + ((64 + quad * 16) ^ sw));
                floatx4 acc;
#pragma unroll
                for (int r = 0; r < 4; r++) {
                    float dotv = *(const float*)(smem + OFF_SDD + (jt * 16 + quad * 4 + r) * 4);
                    acc[r] = b1v + dotv * w1dv;
                }
                acc = MFMA16(ra0, BW1[0], acc);
                acc = MFMA16(ra1, BW1[1], acc);
#pragma unroll
                for (int r = 0; r < 4; r++)
                    *(float*)(smem + OFF_R + (quad * 4 + r) * 528 + c0 * 4) = acc[r];
            }
            __syncthreads();
            // (c) strips for this jt: head h = w.  x' = kp'+qp'+R = log2e * t1.
            {
                const int jr = j0 + jt * 16 + l15;   // Kpb row
                bf16x8 A[4];
#pragma unroll
                for (int f = 0; f < 4; f++) {
                    const int c8 = f * 32 + quad * 8;
                    bf16x8 kp = *(const bf16x8*)(Kpb + ((size_t)w * N + jr) * HIDN + c8);
                    bf16x8 qp = *(const bf16x8*)(smem + OFF_QPB + (w * HIDN + c8) * 2);
                    const char* rbase = smem + OFF_R + l15 * 528 + c8 * 4;
                    float4 r0 = *(const float4*)(rbase);
                    float4 r1 = *(const float4*)(rbase + 16);
                    float xs[8] = {r0.x, r0.y, r0.z, r0.w, r1.x, r1.y, r1.z, r1.w};
                    union { unsigned int u[4]; bf16x8 v; } uu;
#pragma unroll
                    for (int e2 = 0; e2 < 4; e2++) {
                        float xa = silu2_fast(bf2f(kp[2 * e2])     + bf2f(qp[2 * e2])     + xs[2 * e2]);
                        float xb = silu2_fast(bf2f(kp[2 * e2 + 1]) + bf2f(qp[2 * e2 + 1]) + xs[2 * e2 + 1]);
                        uu.u[e2] = cvt_pk_bf16(xa, xb);
                    }
                    A[f] = uu.v;   // s1 = log2e * x1 (bf16)
                }
                float part[4] = {0.f, 0.f, 0.f, 0.f};
#pragma unroll 2
                for (int ct = 0; ct < 8; ct++) {
                    const int rw2 = ct * 16 + l15;
                    const char* wb = smem + OFF_W2T + rw2 * 256;
                    const int sw = (rw2 & 7) << 4;
                    bf16x8 b0 = *(const bf16x8*)(wb + ((quad * 16) ^ sw));
                    bf16x8 b1 = *(const bf16x8*)(wb + ((64 + quad * 16) ^ sw));
                    bf16x8 b2 = *(const bf16x8*)(wb + ((128 + quad * 16) ^ sw));
                    bf16x8 b3 = *(const bf16x8*)(wb + ((192 + quad * 16) ^ sw));
                    float bb = *(const float*)(smem + OFF_B2 + rw2 * 4);      // b2 * log2e
                    float ww = *(const float*)(smem + OFF_W3T + (w * 128 + rw2) * 4);  // w3 * ln2
                    // acc = s1 @ W2 + b2*log2e = log2e * t2   (log2e*x1 @ W2... NOTE:
                    // s1 = log2e*x1, so s1@W2 = log2e*(x1@W2); + b2*log2e = log2e*t2. exact.)
                    floatx4 acc = {bb, bb, bb, bb};
                    acc = MFMA16(A[0], b0, acc);
                    acc = MFMA16(A[1], b1, acc);
                    acc = MFMA16(A[2], b2, acc);
                    acc = MFMA16(A[3], b3, acc);
#pragma unroll
                    for (int r = 0; r < 4; r++)
                        part[r] += silu2_fast(acc[r]) * ww;   // (log2e*x2)*(w3*ln2) = x2*w3
                }
#pragma unroll
                for (int off = 1; off < 16; off <<= 1) {
#pragma unroll
                    for (int r = 0; r < 4; r++)
                        part[r] += __shfl_xor(part[r], off, 64);
                }
                if (l15 == 0) {
                    const int jo = j0 + jt * 16 + quad * 4;
                    float4 mv = *(const float4*)(mask + (size_t)i * N + jo);
                    float4 sv;
                    sv.x = fminf(fmaxf(part[0] + ab3v + mv.x, -1e9f), 1e9f);
                    sv.y = fminf(fmaxf(part[1] + ab3v + mv.y, -1e9f), 1e9f);
                    sv.z = fminf(fmaxf(part[2] + ab3v + mv.z, -1e9f), 1e9f);
                    sv.w = fminf(fmaxf(part[3] + ab3v + mv.w, -1e9f), 1e9f);
                    *(float4*)(scores + ((size_t)w * N + i) * N + jo) = sv;
                }
            }
            __syncthreads();
        }
    }
}

// K3: softmax + attn@V + coords + fused LN.  512 threads, 8 waves,
// ONE head per wave.  (round-11 proven version, unchanged)
__global__ __launch_bounds__(512) void k_attn2(
    const float* __restrict__ scores, const float* __restrict__ v,
    const float* __restrict__ gates, const float* __restrict__ coords,
    const float* __restrict__ ef, const float* __restrict__ wo,
    const float* __restrict__ bo, const float* __restrict__ lng,
    const float* __restrict__ lnb, float* __restrict__ out) {
    __shared__ float sA[NHD][N];
    __shared__ float sCrd[N * 3];
    __shared__ float sC[NHD][3];
    __shared__ float sUpd[HIDN];
    __shared__ float sP[3][HIDN];
    __shared__ float sR2[2];
    int i = blockIdx.x, t = threadIdx.x, w = t >> 6, lane = t & 63;
    for (int idx = t; idx < N * 3; idx += 512) sCrd[idx] = coords[idx];
    float cix = coords[i * 3], ciy = coords[i * 3 + 1], ciz = coords[i * 3 + 2];
    __syncthreads();
    {
        const int h = w;
        const float* srow = scores + ((size_t)h * N + i) * N;
        float s[6];
#pragma unroll
        for (int p = 0; p < 6; p++) s[p] = srow[lane + 64 * p];
        float m = s[0];
#pragma unroll
        for (int p = 1; p < 6; p++) m = fmaxf(m, s[p]);
        for (int off = 1; off < 64; off <<= 1) m = fmaxf(m, __shfl_xor(m, off, 64));
        float e[6], sum = 0.f;
#pragma unroll
        for (int p = 0; p < 6; p++) { e[p] = __expf(s[p] - m); sum += e[p]; }
        for (int off = 1; off < 64; off <<= 1) sum += __shfl_xor(sum, off, 64);
        float inv = 1.0f / sum;
#pragma unroll
        for (int p = 0; p < 6; p++) sA[w][lane + 64 * p] = e[p] * inv;
        // feats (wave-local sA): d4 = lane&3, grp = lane>>2
        int d4 = lane & 3, grp = lane >> 2;
        float4 f4 = {0.f, 0.f, 0.f, 0.f};
        for (int j = grp; j < N; j += 16) {
            float a = sA[w][j];
            float4 vv = *(const float4*)(v + j * HIDN + h * DHD + d4 * 4);
            f4.x += a * vv.x; f4.y += a * vv.y; f4.z += a * vv.z; f4.w += a * vv.w;
        }
#pragma unroll
        for (int off = 4; off < 64; off <<= 1) {
            f4.x += __shfl_xor(f4.x, off, 64);
            f4.y += __shfl_xor(f4.y, off, 64);
            f4.z += __shfl_xor(f4.z, off, 64);
            f4.w += __shfl_xor(f4.w, off, 64);
        }
        if (lane < 4) *(float4*)(&sUpd[h * DHD + lane * 4]) = f4;
        // coords partial (wave-local)
        float cx = 0.f, cy = 0.f, cz = 0.f;
#pragma unroll
        for (int p = 0; p < 6; p++) {
            int j = lane + 64 * p;
            float a = sA[w][j];
            cx += a * (cix - sCrd[j * 3]);
            cy += a * (ciy - sCrd[j * 3 + 1]);
            cz += a * (ciz - sCrd[j * 3 + 2]);
        }
        for (int off = 1; off < 64; off <<= 1) {
            cx += __shfl_xor(cx, off, 64);
            cy += __shfl_xor(cy, off, 64);
            cz += __shfl_xor(cz, off, 64);
        }
        if (lane == 0) {
            float g = gates[i * NHD + h] * (1.0f / NHD);
            sC[h][0] = g * cx; sC[h][1] = g * cy; sC[h][2] = g * cz;
        }
    }
    __syncthreads();
    if (t < 3) {
        float acc = coords[i * 3 + t];
#pragma unroll
        for (int h = 0; h < NHD; h++) acc += sC[h][t];
        out[N * HIDN + i * 3 + t] = acc;
    }
    // fused LN: y = ef + sUpd@wo + bo.  Dot split 4 ways across 512 threads.
    int c = t & 127, g = t >> 7;
    float y = (g == 0) ? (ef[i * HIDN + c] + bo[c]) : 0.f;
#pragma unroll 8
    for (int cp = 0; cp < 32; cp++) {
        int cc = g * 32 + cp;
        y += sUpd[cc] * wo[cc * HIDN + c];
    }
    if (g > 0) sP[g - 1][c] = y;
    __syncthreads();
    if (g == 0) y += sP[0][c] + sP[1][c] + sP[2][c];
    float ssum = wave_sum(y);
    if (t < 128 && (t & 63) == 0) sR2[t >> 6] = ssum;
    __syncthreads();
    float mu = (sR2[0] + sR2[1]) * (1.0f / HIDN);
    __syncthreads();
    float dv = y - mu;
    float s2 = wave_sum(dv * dv);
    if (t < 128 && (t & 63) == 0) sR2[t >> 6] = s2;
    __syncthreads();
    float var = (sR2[0] + sR2[1]) * (1.0f / HIDN);
    if (t < 128) out[i * HIDN + c] = dv * rsqrtf(var + 1e-5f) * lng[c] + lnb[c];
}

extern "C" void kernel_launch(void* const* d_in, const int* in_sizes, int n_in,
                              void* d_out, int out_size, void* d_ws, size_t ws_size,
                              hipStream_t stream) {
    const float* ef      = (const float*)d_in[0];
    const float* coords  = (const float*)d_in[1];
    const float* mask    = (const float*)d_in[2];
    const float* wq      = (const float*)d_in[3];
    const float* wk      = (const float*)d_in[4];
    const float* wv      = (const float*)d_in[5];
    const float* centers = (const float*)d_in[6];
    const float* widths  = (const float*)d_in[7];
    const float* aw1     = (const float*)d_in[8];
    const float* ab1     = (const float*)d_in[9];
    const float* aw2     = (const float*)d_in[10];
    const float* ab2     = (const float*)d_in[11];
    const float* aw3     = (const float*)d_in[12];
    const float* ab3     = (const float*)d_in[13];
    const float* gw1     = (const float*)d_in[14];
    const float* gb1     = (const float*)d_in[15];
    const float* gw2     = (const float*)d_in[16];
    const float* gb2     = (const float*)d_in[17];
    const float* wo      = (const float*)d_in[18];
    const float* bo      = (const float*)d_in[19];
    const float* lng     = (const float*)d_in[20];
    const float* lnb     = (const float*)d_in[21];
    float* ws = (float*)d_ws;
    float* v      = ws + WS_V;
    unsigned short* Qpb = (unsigned short*)(ws + WS_QPB);
    unsigned short* Kpb = (unsigned short*)(ws + WS_KPB);
    float* gates  = ws + WS_GATE;
    float* scores = ws + WS_SCORES;
    unsigned short* w2bf = (unsigned short*)(ws + WS_W2BF);
    float* out = (float*)d_out;

    k_pre<<<N, 128, 0, stream>>>(ef, wq, wk, wv, aw1, aw2, gw1, gb1, gw2, gb2, v, Qpb, Kpb, gates, w2bf);
    k_scores_mfma<<<dim3(4, N), 512, 0, stream>>>(
        coords, mask, centers, widths, aw1, ab1, ab2, aw3, ab3, Qpb, Kpb, w2bf, scores);
    k_attn2<<<N, 512, 0, stream>>>(scores, v, gates, coords, ef, wo, bo, lng, lnb, out);
}